// Round 2
// baseline (109.698 us; speedup 1.0000x reference)
//
#include <hip/hip_runtime.h>
#include <hip/hip_bf16.h>

typedef __bf16 bf16x8 __attribute__((ext_vector_type(8)));
typedef float f32x16 __attribute__((ext_vector_type(16)));
typedef unsigned int u32x4 __attribute__((ext_vector_type(4)));
typedef unsigned short u16;

// Problem constants: T=16, N=128, D=512, M=4096, TEMP=0.1
// ws layout: zn bf16[4096*512] (4 MiB) | expsum f32[4096] | possum f32[4096]
// done input is provably dead: positive_mask reduces to block-diag(32) + eye,
// so every row has exactly 31 positives (its trajectory group across 2 views).

__device__ inline void async_cp16(const u16* g, u16* l) {
    // gfx950 global->LDS DMA, 16B/lane; LDS dest = wave-uniform base + lane*16
    __builtin_amdgcn_global_load_lds(
        (const __attribute__((address_space(1))) unsigned int*)g,
        (__attribute__((address_space(3))) unsigned int*)l, 16, 0, 0);
}

// ---------------------------------------------------------------- normalize
__global__ void nrm_kernel(const float* __restrict__ z, u16* __restrict__ zn,
                           float* __restrict__ expsum, float* __restrict__ possum) {
    int row = blockIdx.x;          // 4096 rows
    int tid = threadIdx.x;         // 128 threads, 4 floats each
    float4 v = ((const float4*)(z + row * 512))[tid];
    float ss = v.x * v.x + v.y * v.y + v.z * v.z + v.w * v.w;
#pragma unroll
    for (int off = 32; off; off >>= 1) ss += __shfl_down(ss, off, 64);
    __shared__ float red[2];
    if ((tid & 63) == 0) red[tid >> 6] = ss;
    __syncthreads();
    float sc = 1.0f / fmaxf(sqrtf(red[0] + red[1]), 1e-8f);
    __hip_bfloat16 b[4];
    b[0] = __float2bfloat16(v.x * sc);
    b[1] = __float2bfloat16(v.y * sc);
    b[2] = __float2bfloat16(v.z * sc);
    b[3] = __float2bfloat16(v.w * sc);
    uint2 p;
    __builtin_memcpy(&p, b, 8);
    ((uint2*)(zn + row * 512))[tid] = p;
    if (tid == 0) { expsum[row] = 0.f; possum[row] = 0.f; }
}

// ---------------------------------------------------------------- positives
// Group g: rows {g*16..+15} U {2048+g*16..+15}. One wave: 32x32 Gram via MFMA
// (same frag as A and B => Z Z^T), mask diagonal, row-reduce.
__global__ void pos_kernel(const u16* __restrict__ zn, float* __restrict__ possum) {
    int g = blockIdx.x;
    int l = threadIdx.x;           // 64
    int u = l & 31, h = l >> 5;
    int grow = (u < 16) ? (g * 16 + u) : (2048 + g * 16 + (u - 16));
    const u32x4* src = (const u32x4*)(zn + grow * 512);
    f32x16 acc = {};
#pragma unroll
    for (int kc = 0; kc < 32; ++kc) {
        bf16x8 f = __builtin_bit_cast(bf16x8, src[h + 2 * kc]);
        acc = __builtin_amdgcn_mfma_f32_32x32x16_bf16(f, f, acc, 0, 0, 0);
    }
#pragma unroll
    for (int r = 0; r < 16; ++r) {
        int rrow = (r & 3) + 8 * (r >> 2) + 4 * h;   // C/D: col=lane&31
        float v = (rrow == u) ? 0.f : acc[r];
        v += __shfl_xor(v, 1, 64);
        v += __shfl_xor(v, 2, 64);
        v += __shfl_xor(v, 4, 64);
        v += __shfl_xor(v, 8, 64);
        v += __shfl_xor(v, 16, 64);
        if (u == 0) {
            int gr = (rrow < 16) ? (g * 16 + rrow) : (2048 + g * 16 + (rrow - 16));
            possum[gr] = v * 10.0f;
        }
    }
}

// ---------------------------------------------------------------- fused GEMM
// Upper-triangular 128x128 block-tiles (symmetry halves work): 528 WGs.
// Wave holds 32 rows of A (full K=512) in 128 VGPRs. B: 4 tiles of 32 cols,
// async-staged into double-buffered LDS (XOR granule swizzle: granule g of
// col c at slot g^(c&7) -- conflict-free b128 reads, global_load_lds-legal).
// Off-diagonal WGs also emit column sums (transpose contribution).
__global__ __launch_bounds__(256, 2) void gemm_kernel(const u16* __restrict__ zn,
                                                      float* __restrict__ expsum) {
    __shared__ u16 Bt[2][32 * 512];   // 2 x 32 KB
    int wave = threadIdx.x >> 6;
    int l = threadIdx.x & 63;
    int m = l & 31, h = l >> 5;

    // linear block -> (i,j), i<=j, 32x32 blocks of 128 rows/cols
    int t = blockIdx.x, i = 0;
    while (t >= 32 - i) { t -= 32 - i; ++i; }
    int j = i + t;
    int rowbase = i * 128 + wave * 32;
    bool diagwg = (i == j);

    // A fragments, full K: granule (h + 2*kc) of row rowbase+m
    u32x4 a[32];
    const u32x4* arow = (const u32x4*)(zn + (size_t)(rowbase + m) * 512);
#pragma unroll
    for (int kc = 0; kc < 32; ++kc) a[kc] = arow[h + 2 * kc];

    float expacc[16];
#pragma unroll
    for (int r = 0; r < 16; ++r) expacc[r] = 0.f;

    // stage tile 0 (async)
    {
        int colbase = j * 128;
#pragma unroll
        for (int it = 0; it < 8; ++it) {
            int col = wave * 8 + it;
            int s = col & 7;
            async_cp16(zn + (size_t)(colbase + col) * 512 + ((l ^ s) * 8),
                       &Bt[0][col * 512]);
        }
    }

    int sB = m & 7;
    for (int ct = 0; ct < 4; ++ct) {
        __syncthreads();              // drains stage(ct); frees buf[(ct+1)&1]
        if (ct < 3) {                 // prefetch next tile while computing
            int colbase = j * 128 + (ct + 1) * 32;
            u16* dst = &Bt[(ct + 1) & 1][0];
#pragma unroll
            for (int it = 0; it < 8; ++it) {
                int col = wave * 8 + it;
                int s = col & 7;
                async_cp16(zn + (size_t)(colbase + col) * 512 + ((l ^ s) * 8),
                           dst + col * 512);
            }
        }
        const u16* bcol = &Bt[ct & 1][m * 512];
        f32x16 acc0 = {}, acc1 = {};  // 2 independent chains for MFMA latency
#pragma unroll
        for (int kc = 0; kc < 16; ++kc) {
            bf16x8 b0 = *(const bf16x8*)(bcol + (((h + 4 * kc) ^ sB) * 8));
            bf16x8 b1 = *(const bf16x8*)(bcol + (((h + 4 * kc + 2) ^ sB) * 8));
            acc0 = __builtin_amdgcn_mfma_f32_32x32x16_bf16(
                __builtin_bit_cast(bf16x8, a[2 * kc]), b0, acc0, 0, 0, 0);
            acc1 = __builtin_amdgcn_mfma_f32_32x32x16_bf16(
                __builtin_bit_cast(bf16x8, a[2 * kc + 1]), b1, acc1, 0, 0, 0);
        }
        int colbase = j * 128 + ct * 32;
        bool diagtile = diagwg && (ct == wave);
        float cs = 0.f;
#pragma unroll
        for (int r = 0; r < 16; ++r) {
            int rrow = (r & 3) + 8 * (r >> 2) + 4 * h;
            float e = (diagtile && rrow == m)
                          ? 0.f
                          : __expf((acc0[r] + acc1[r]) * 10.0f);
            expacc[r] += e;           // row sums
            cs += e;                  // column sum for this col (lane m), rows of block i
        }
        if (!diagwg) {                // transpose contribution to rows of block j
            cs += __shfl_xor(cs, 32, 64);
            if (h == 0) atomicAdd(&expsum[colbase + m], cs);
        }
    }
    // row sums: reduce over 32 column-lanes, one atomic per row per wave
#pragma unroll
    for (int r = 0; r < 16; ++r) {
        float v = expacc[r];
        v += __shfl_xor(v, 1, 64);
        v += __shfl_xor(v, 2, 64);
        v += __shfl_xor(v, 4, 64);
        v += __shfl_xor(v, 8, 64);
        v += __shfl_xor(v, 16, 64);
        if (m == 0) {
            int rrow = (r & 3) + 8 * (r >> 2) + 4 * h;
            atomicAdd(&expsum[rowbase + rrow], v);
        }
    }
}

// ---------------------------------------------------------------- finalize
__global__ void fin_kernel(const float* __restrict__ expsum,
                           const float* __restrict__ possum, float* __restrict__ out) {
    int tid = threadIdx.x;         // 1024
    float s = 0.f;
    for (int i = tid; i < 4096; i += 1024)
        s += __logf(expsum[i]) - possum[i] * (1.0f / 31.0f);
#pragma unroll
    for (int off = 32; off; off >>= 1) s += __shfl_down(s, off, 64);
    __shared__ float red[16];
    if ((tid & 63) == 0) red[tid >> 6] = s;
    __syncthreads();
    if (tid == 0) {
        float t = 0.f;
#pragma unroll
        for (int i = 0; i < 16; ++i) t += red[i];
        out[0] = t * (1.0f / 4096.0f);
    }
}

extern "C" void kernel_launch(void* const* d_in, const int* in_sizes, int n_in,
                              void* d_out, int out_size, void* d_ws, size_t ws_size,
                              hipStream_t stream) {
    const float* z = (const float*)d_in[0];
    u16* zn = (u16*)d_ws;
    float* expsum = (float*)((char*)d_ws + (4u << 20));
    float* possum = expsum + 4096;
    float* out = (float*)d_out;

    nrm_kernel<<<4096, 128, 0, stream>>>(z, zn, expsum, possum);
    pos_kernel<<<128, 64, 0, stream>>>(zn, possum);
    gemm_kernel<<<528, 256, 0, stream>>>(zn, expsum);
    fin_kernel<<<1, 1024, 0, stream>>>(expsum, possum, out);
}

// Round 3
// 99.861 us; speedup vs baseline: 1.0985x; 1.0985x over previous
//
#include <hip/hip_runtime.h>
#include <hip/hip_bf16.h>

typedef float f32x16 __attribute__((ext_vector_type(16)));
typedef unsigned short u16;
typedef unsigned char u8;
typedef unsigned int u32;
typedef unsigned long long u64;
typedef u32 u32x4 __attribute__((ext_vector_type(4)));
typedef u64 u64x2 __attribute__((ext_vector_type(2)));

// T=16, N=128, D=512, M=4096, TEMP=0.1. done is provably dead:
// positive_mask = block-diag(32-row trajectory groups) + eye, 31 positives/row.
// ws: zn8 fp8-e4m3[4096*512] (2 MiB) | expsum f32[4096] | possum f32[4096]

__device__ inline void async_cp16(const u8* g, u8* l) {
    __builtin_amdgcn_global_load_lds(
        (const __attribute__((address_space(1))) unsigned int*)g,
        (__attribute__((address_space(3))) unsigned int*)l, 16, 0, 0);
}

// ---------------------------------------------------------------- normalize
// fp32 row norm (exact), emit fp8-e4m3 unit rows.
__global__ void nrm_kernel(const float* __restrict__ z, u8* __restrict__ zn8,
                           float* __restrict__ expsum, float* __restrict__ possum) {
    int row = blockIdx.x;          // 4096
    int tid = threadIdx.x;         // 128 threads x 4 floats
    float4 v = ((const float4*)(z + row * 512))[tid];
    float ss = v.x * v.x + v.y * v.y + v.z * v.z + v.w * v.w;
#pragma unroll
    for (int off = 32; off; off >>= 1) ss += __shfl_down(ss, off, 64);
    __shared__ float red[2];
    if ((tid & 63) == 0) red[tid >> 6] = ss;
    __syncthreads();
    float sc = 1.0f / fmaxf(sqrtf(red[0] + red[1]), 1e-8f);
    u32 w = __builtin_amdgcn_cvt_pk_fp8_f32(v.x * sc, v.y * sc, 0, false);
    w = __builtin_amdgcn_cvt_pk_fp8_f32(v.z * sc, v.w * sc, w, true);
    ((u32*)(zn8 + (size_t)row * 512))[tid] = w;
    if (tid == 0) { expsum[row] = 0.f; possum[row] = 0.f; }
}

// ---------------------------------------------------------------- positives
// One wave per group: 32x32 Gram via fp8 MFMA (same frag as A and B => Z Z^T).
__global__ void pos_kernel(const u8* __restrict__ zn8, float* __restrict__ possum) {
    int g = blockIdx.x;
    int l = threadIdx.x;           // 64
    int u = l & 31, h = l >> 5;
    int grow = (u < 16) ? (g * 16 + u) : (2048 + g * 16 + (u - 16));
    const u64* src = (const u64*)(zn8 + (size_t)grow * 512);
    f32x16 acc = {};
#pragma unroll
    for (int kc = 0; kc < 32; ++kc) {
        u64 f = src[2 * kc + h];
        acc = __builtin_amdgcn_mfma_f32_32x32x16_fp8_fp8((long)f, (long)f, acc, 0, 0, 0);
    }
#pragma unroll
    for (int r = 0; r < 16; ++r) {
        int rrow = (r & 3) + 8 * (r >> 2) + 4 * h;   // C/D: col=lane&31
        float v = (rrow == u) ? 0.f : acc[r];
        v += __shfl_xor(v, 1, 64);
        v += __shfl_xor(v, 2, 64);
        v += __shfl_xor(v, 4, 64);
        v += __shfl_xor(v, 8, 64);
        v += __shfl_xor(v, 16, 64);
        if (u == 0) {
            int gr = (rrow < 16) ? (g * 16 + rrow) : (2048 + g * 16 + (rrow - 16));
            possum[gr] = v * 10.0f;
        }
    }
}

// ---------------------------------------------------------------- fused GEMM
// Upper-tri 128x128 block-tiles (528 WGs). A: 32 rows x K=512 fp8 resident in
// 64 VGPRs/lane (loaded as full 16B granules, k-half kept via cndmask). B: 4
// tiles of 32 cols, async global_load_lds into double-buffered LDS (16 KB),
// slot = granule ^ (col&7) swizzle for near-conflict-free ds_read_b64.
__global__ __launch_bounds__(256, 2) void gemm_kernel(const u8* __restrict__ zn8,
                                                      float* __restrict__ expsum) {
    __shared__ u8 Bt[2][32 * 512];   // 2 x 16 KB
    int wave = threadIdx.x >> 6;
    int l = threadIdx.x & 63;
    int m = l & 31, h = l >> 5;

    int t = blockIdx.x, i = 0;       // linear -> (i,j), i<=j, 32 blocks of 128
    while (t >= 32 - i) { t -= 32 - i; ++i; }
    int j = i + t;
    int rowbase = i * 128 + wave * 32;
    bool diagwg = (i == j);

    // A resident: af[kc] = 8 fp8 (k = kc*16 + h*8 ..+7) of row rowbase+m
    long af[32];
    {
        const u32x4* arow = (const u32x4*)(zn8 + (size_t)(rowbase + m) * 512);
#pragma unroll
        for (int p = 0; p < 2; ++p) {
            u32x4 t16[16];
#pragma unroll
            for (int g2 = 0; g2 < 16; ++g2) t16[g2] = arow[p * 16 + g2];
#pragma unroll
            for (int g2 = 0; g2 < 16; ++g2) {
                u64x2 q = __builtin_bit_cast(u64x2, t16[g2]);
                af[p * 16 + g2] = (long)(h ? q.y : q.x);
            }
        }
    }

    float expacc[16];
#pragma unroll
    for (int r = 0; r < 16; ++r) expacc[r] = 0.f;

    // staging: wave w covers local cols 8w..8w+7; one instr = 2 cols (1 KB)
    auto stage = [&](int buf, int ct) {
        int colbase = j * 128 + ct * 32;
#pragma unroll
        for (int it = 0; it < 4; ++it) {
            int c = wave * 8 + 2 * it;
            int C = colbase + c + h;                 // per-lane column
            int srcoff = (m ^ (C & 7)) * 16;         // granule swizzle
            async_cp16(zn8 + (size_t)C * 512 + srcoff, &Bt[buf][c * 512]);
        }
    };

    stage(0, 0);
    int sB16 = (m & 7) * 16;
    for (int ct = 0; ct < 4; ++ct) {
        __syncthreads();             // drains stage(ct)
        if (ct < 3) stage((ct + 1) & 1, ct + 1);
        const u8* bcol = &Bt[ct & 1][m * 512 + h * 8];
        f32x16 acc = {};
#pragma unroll
        for (int kc = 0; kc < 32; ++kc) {
            u64 bf = *(const u64*)(bcol + ((kc * 16) ^ sB16));
            acc = __builtin_amdgcn_mfma_f32_32x32x16_fp8_fp8(af[kc], (long)bf, acc, 0, 0, 0);
        }
        int colbase = j * 128 + ct * 32;
        bool diagtile = diagwg && (ct == wave);
        float cs = 0.f;
#pragma unroll
        for (int r = 0; r < 16; ++r) {
            int rrow = (r & 3) + 8 * (r >> 2) + 4 * h;
            float e = (diagtile && rrow == m) ? 0.f : __expf(acc[r] * 10.0f);
            expacc[r] += e;          // row sums (rows of block i)
            cs += e;                 // column sum (col m of this tile)
        }
        if (!diagwg) {               // transpose contribution -> rows of block j
            cs += __shfl_xor(cs, 32, 64);
            if (h == 0) atomicAdd(&expsum[colbase + m], cs);
        }
    }
#pragma unroll
    for (int r = 0; r < 16; ++r) {
        float v = expacc[r];
        v += __shfl_xor(v, 1, 64);
        v += __shfl_xor(v, 2, 64);
        v += __shfl_xor(v, 4, 64);
        v += __shfl_xor(v, 8, 64);
        v += __shfl_xor(v, 16, 64);
        if (m == 0) {
            int rrow = (r & 3) + 8 * (r >> 2) + 4 * h;
            atomicAdd(&expsum[rowbase + rrow], v);
        }
    }
}

// ---------------------------------------------------------------- finalize
__global__ void fin_kernel(const float* __restrict__ expsum,
                           const float* __restrict__ possum, float* __restrict__ out) {
    int tid = threadIdx.x;         // 1024
    float s = 0.f;
    for (int i = tid; i < 4096; i += 1024)
        s += __logf(expsum[i]) - possum[i] * (1.0f / 31.0f);
#pragma unroll
    for (int off = 32; off; off >>= 1) s += __shfl_down(s, off, 64);
    __shared__ float red[16];
    if ((tid & 63) == 0) red[tid >> 6] = s;
    __syncthreads();
    if (tid == 0) {
        float tt = 0.f;
#pragma unroll
        for (int i2 = 0; i2 < 16; ++i2) tt += red[i2];
        out[0] = tt * (1.0f / 4096.0f);
    }
}

extern "C" void kernel_launch(void* const* d_in, const int* in_sizes, int n_in,
                              void* d_out, int out_size, void* d_ws, size_t ws_size,
                              hipStream_t stream) {
    const float* z = (const float*)d_in[0];
    u8* zn8 = (u8*)d_ws;
    float* expsum = (float*)((char*)d_ws + (2u << 20));
    float* possum = expsum + 4096;
    float* out = (float*)d_out;

    nrm_kernel<<<4096, 128, 0, stream>>>(z, zn8, expsum, possum);
    pos_kernel<<<128, 64, 0, stream>>>(zn8, possum);
    gemm_kernel<<<528, 256, 0, stream>>>(zn8, expsum);
    fin_kernel<<<1, 1024, 0, stream>>>(expsum, possum, out);
}

// Round 4
// 99.399 us; speedup vs baseline: 1.1036x; 1.0046x over previous
//
#include <hip/hip_runtime.h>
#include <hip/hip_bf16.h>

typedef float f32x16 __attribute__((ext_vector_type(16)));
typedef unsigned short u16;
typedef unsigned char u8;
typedef unsigned int u32;
typedef unsigned long long u64;

// T=16, N=128, D=512, M=4096, TEMP=0.1. done is provably dead:
// positive_mask = block-diag(32-row trajectory groups) + eye, 31 positives/row.
// ws: zn8 fp8-e4m3[4096*512] (2 MiB) | part f32[32][32][128] (512 KB) | possum f32[4096]
// part[b][s][r]: contribution to expsum of row b*128+r from source-slot s.
// WG (i,j): row-sums -> part[i][j][*]; col-sums (i<j) -> part[j][i][*].
// Every slot written exactly once => no zero-init, no atomics anywhere.

__device__ inline void async_cp16(const u8* g, u8* l) {
    __builtin_amdgcn_global_load_lds(
        (const __attribute__((address_space(1))) unsigned int*)g,
        (__attribute__((address_space(3))) unsigned int*)l, 16, 0, 0);
}

// ---------------------------------------------------------------- normalize
__global__ void nrm_kernel(const float* __restrict__ z, u8* __restrict__ zn8) {
    int row = blockIdx.x;          // 4096
    int tid = threadIdx.x;         // 128 threads x 4 floats
    float4 v = ((const float4*)(z + row * 512))[tid];
    float ss = v.x * v.x + v.y * v.y + v.z * v.z + v.w * v.w;
#pragma unroll
    for (int off = 32; off; off >>= 1) ss += __shfl_down(ss, off, 64);
    __shared__ float red[2];
    if ((tid & 63) == 0) red[tid >> 6] = ss;
    __syncthreads();
    float sc = 1.0f / fmaxf(sqrtf(red[0] + red[1]), 1e-8f);
    u32 w = __builtin_amdgcn_cvt_pk_fp8_f32(v.x * sc, v.y * sc, 0, false);
    w = __builtin_amdgcn_cvt_pk_fp8_f32(v.z * sc, v.w * sc, w, true);
    ((u32*)(zn8 + (size_t)row * 512))[tid] = w;
}

// ---------------------------------------------------------------- positives
// One wave per trajectory group: 32x32 Gram via fp8 MFMA (A==B => Z Z^T).
__global__ void pos_kernel(const u8* __restrict__ zn8, float* __restrict__ possum) {
    int g = blockIdx.x;
    int l = threadIdx.x;           // 64
    int u = l & 31, h = l >> 5;
    int grow = (u < 16) ? (g * 16 + u) : (2048 + g * 16 + (u - 16));
    const u64* src = (const u64*)(zn8 + (size_t)grow * 512);
    f32x16 acc = {};
#pragma unroll
    for (int kc = 0; kc < 32; ++kc) {
        u64 f = src[2 * kc + h];
        acc = __builtin_amdgcn_mfma_f32_32x32x16_fp8_fp8((long)f, (long)f, acc, 0, 0, 0);
    }
#pragma unroll
    for (int r = 0; r < 16; ++r) {
        int rrow = (r & 3) + 8 * (r >> 2) + 4 * h;   // C/D: col=lane&31
        float v = (rrow == u) ? 0.f : acc[r];
        v += __shfl_xor(v, 1, 64);
        v += __shfl_xor(v, 2, 64);
        v += __shfl_xor(v, 4, 64);
        v += __shfl_xor(v, 8, 64);
        v += __shfl_xor(v, 16, 64);
        if (u == 0) {
            int gr = (rrow < 16) ? (g * 16 + rrow) : (2048 + g * 16 + (rrow - 16));
            possum[gr] = v * 10.0f;
        }
    }
}

// ---------------------------------------------------------------- fused GEMM
// Upper-tri 128x128 block-tiles (528 WGs). A: 32 rows x K=512 fp8 resident in
// 64 VGPRs/lane. B: 4 tiles of 32 cols via async global_load_lds, double
// buffered, slot = granule ^ (col&7) swizzle. All output via plain stores.
__global__ __launch_bounds__(256, 3) void gemm_kernel(const u8* __restrict__ zn8,
                                                      float* __restrict__ part) {
    __shared__ u8 Bt[2][32 * 512];        // 32 KB
    __shared__ float colred[4][4][32];    // [wave][tile][col], 2 KB
    __shared__ float rowred[128];         // 512 B
    int wave = threadIdx.x >> 6;
    int l = threadIdx.x & 63;
    int m = l & 31, h = l >> 5;

    int t = blockIdx.x, i = 0;            // linear -> (i,j), i<=j
    while (t >= 32 - i) { t -= 32 - i; ++i; }
    int j = i + t;
    int rowbase = i * 128 + wave * 32;
    bool diagwg = (i == j);

    // A resident: af[kc] = fp8 k in [kc*16 + h*8, +8) of row rowbase+m
    long af[32];
    {
        const u8* arow = zn8 + (size_t)(rowbase + m) * 512 + h * 8;
#pragma unroll
        for (int kc = 0; kc < 32; ++kc) af[kc] = *(const long*)(arow + kc * 16);
    }

    float expacc[16];
#pragma unroll
    for (int r = 0; r < 16; ++r) expacc[r] = 0.f;

    auto stage = [&](int buf, int ct) {   // wave w: local cols 8w..8w+7
        int colbase = j * 128 + ct * 32;
#pragma unroll
        for (int it = 0; it < 4; ++it) {
            int c = wave * 8 + 2 * it;
            int C = colbase + c + h;      // lanes 0-31: col c, lanes 32-63: c+1
            int srcoff = (m ^ (C & 7)) * 16;
            async_cp16(zn8 + (size_t)C * 512 + srcoff, &Bt[buf][c * 512]);
        }
    };

    stage(0, 0);
    int sB16 = (m & 7) * 16;
    for (int ct = 0; ct < 4; ++ct) {
        __syncthreads();                  // stage(ct) landed
        if (ct < 3) stage((ct + 1) & 1, ct + 1);
        const u8* bcol = &Bt[ct & 1][m * 512 + h * 8];
        f32x16 acc = {};
#pragma unroll
        for (int kc = 0; kc < 32; ++kc) {
            u64 bf = *(const u64*)(bcol + ((kc * 16) ^ sB16));
            acc = __builtin_amdgcn_mfma_f32_32x32x16_fp8_fp8(af[kc], (long)bf, acc, 0, 0, 0);
        }
        bool diagtile = diagwg && (ct == wave);
        float cs = 0.f;
#pragma unroll
        for (int r = 0; r < 16; ++r) {
            int rrow = (r & 3) + 8 * (r >> 2) + 4 * h;
            float e = (diagtile && rrow == m) ? 0.f : __expf(acc[r] * 10.0f);
            expacc[r] += e;               // row accumulation (over all 128 cols)
            cs += e;                      // col m, this wave's 16 rows (this h)
        }
        cs += __shfl_xor(cs, 32, 64);     // fold h: col m over wave's 32 rows
        if (h == 0) colred[wave][ct][m] = cs;
    }

    // row sums -> rowred (LDS), cross-wave col sums after barrier
#pragma unroll
    for (int r = 0; r < 16; ++r) {
        float v = expacc[r];
        v += __shfl_xor(v, 1, 64);
        v += __shfl_xor(v, 2, 64);
        v += __shfl_xor(v, 4, 64);
        v += __shfl_xor(v, 8, 64);
        v += __shfl_xor(v, 16, 64);
        if (m == 0) {
            int rrow = (r & 3) + 8 * (r >> 2) + 4 * h;
            rowred[wave * 32 + rrow] = v;
        }
    }
    __syncthreads();
    if (threadIdx.x < 128) {
        int tid = threadIdx.x;
        // row-sum contribution of WG(i,j) to block i, slot j
        part[(size_t)(i * 32 + j) * 128 + tid] = rowred[tid];
        if (!diagwg) {                    // transpose: block j, slot i
            int tt = tid >> 5, c2 = tid & 31;
            float cv = colred[0][tt][c2] + colred[1][tt][c2] +
                       colred[2][tt][c2] + colred[3][tt][c2];
            part[(size_t)(j * 32 + i) * 128 + tid] = cv;
        }
    }
}

// ---------------------------------------------------------------- finalize
__global__ void fin_kernel(const float* __restrict__ part,
                           const float* __restrict__ possum, float* __restrict__ out) {
    int tid = threadIdx.x;         // 1024
    float s = 0.f;
    for (int r = tid; r < 4096; r += 1024) {
        int b = r >> 7, rr = r & 127;
        float es = 0.f;
#pragma unroll
        for (int sl = 0; sl < 32; ++sl) es += part[(size_t)(b * 32 + sl) * 128 + rr];
        s += __logf(es) - possum[r] * (1.0f / 31.0f);
    }
#pragma unroll
    for (int off = 32; off; off >>= 1) s += __shfl_down(s, off, 64);
    __shared__ float red[16];
    if ((tid & 63) == 0) red[tid >> 6] = s;
    __syncthreads();
    if (tid == 0) {
        float tt = 0.f;
#pragma unroll
        for (int i2 = 0; i2 < 16; ++i2) tt += red[i2];
        out[0] = tt * (1.0f / 4096.0f);
    }
}

extern "C" void kernel_launch(void* const* d_in, const int* in_sizes, int n_in,
                              void* d_out, int out_size, void* d_ws, size_t ws_size,
                              hipStream_t stream) {
    const float* z = (const float*)d_in[0];
    u8* zn8 = (u8*)d_ws;
    float* part = (float*)((char*)d_ws + (2u << 20));
    float* possum = part + 32 * 32 * 128;
    float* out = (float*)d_out;

    nrm_kernel<<<4096, 128, 0, stream>>>(z, zn8);
    pos_kernel<<<128, 64, 0, stream>>>(zn8, possum);
    gemm_kernel<<<528, 256, 0, stream>>>(zn8, part);
    fin_kernel<<<1, 1024, 0, stream>>>(part, possum, out);
}